// Round 13
// baseline (609.982 us; speedup 1.0000x reference)
//
#include <hip/hip_runtime.h>
#include <math.h>

#define B_DIM 4096
#define S_DIM 200
#define E_DIM 100
#define C_DIM 20
#define K_DIM 51
#define PADW  25

typedef _Float16 f16x8 __attribute__((ext_vector_type(8)));
typedef float    f32x4 __attribute__((ext_vector_type(4)));

// LDS geometry: gT only (no xn buffer)
#define GT_PITCH 80                        // 32 f16 + 16B pad (bank-skew)
#define GT_ROWS  258
#define GT_BYTES (GT_ROWS * GT_PITCH)      // 20640

// d_ws layout
#define NWC (K_DIM * 2 * 512)              // conv A-frags (k, mt): 52224 shorts

static __device__ __forceinline__ unsigned pkrtz(float a, float b) {
    typedef __fp16 fp16v2 __attribute__((ext_vector_type(2)));
    fp16v2 h = __builtin_amdgcn_cvt_pkrtz(a, b);
    unsigned u; __builtin_memcpy(&u, &h, 4); return u;
}

// ---------------------------------------------------------------------------
// Prep: conv A-frags w*256 f16 [frag=(k*2+mt)] (r10-12 layout), Lt[e*20+c]
// (r7/r8-verified), rnl[c] = 1/||label_c||.
// Frag elem: lane l, j -> A[o = mt*16 + (l&15)][i = (l>>4)*8 + j]
// ---------------------------------------------------------------------------
__global__ void prep_kernel(const float* __restrict__ conv_w,
                            const float* __restrict__ labels,
                            short* __restrict__ wAc,
                            float* __restrict__ Lt,
                            float* __restrict__ rnl) {
    int idx = blockIdx.x * 256 + threadIdx.x;
    if (idx < NWC) {
        int frag = idx >> 9;            // k*2 + mt
        int r    = idx & 511;
        int lane = r >> 3, j = r & 7;
        int mt = frag & 1, k = frag >> 1;
        int o = mt * 16 + (lane & 15);
        int i = (lane >> 4) * 8 + j;
        float v = 0.f;
        if (o < C_DIM && i < C_DIM) v = conv_w[(o * C_DIM + i) * K_DIM + k] * 256.f;
        _Float16 h = (_Float16)v;
        unsigned short bits; __builtin_memcpy(&bits, &h, 2);
        wAc[idx] = (short)bits;
    } else if (idx < NWC + C_DIM * E_DIM) {
        int t = idx - NWC;
        int e = t / C_DIM, c = t % C_DIM;
        Lt[t] = labels[c * E_DIM + e];
    } else if (idx < NWC + C_DIM * E_DIM + C_DIM) {
        int c = idx - NWC - C_DIM * E_DIM;
        float s = 0.f;
        for (int ee = 0; ee < E_DIM; ++ee) {
            float lv = labels[c * E_DIM + ee];
            s += lv * lv;
        }
        float nn = sqrtf(s);
        rnl[c] = (nn > 0.f) ? 1.f / nn : 0.f;
    }
}

// ---------------------------------------------------------------------------
// Conv phase-ring (single f16 image, pitch 80 — as r10-12).
// ---------------------------------------------------------------------------
template <int CNT>
__device__ __forceinline__ void conv_tiles(const short* __restrict__ wAc,
                                           const char* gbase,
                                           f32x4 (&acc)[4][2],
                                           int lane) {
#define LDFRAG(k, mt) (*(const f16x8*)(wAc + ((k) * 2 + (mt)) * 512 + lane * 8))
#pragma unroll 1
    for (int p = 0; p < 16; ++p) {
        f16x8 a0[4], a1[4];
#pragma unroll
        for (int j = 0; j < 4; ++j) {
            const int k = p + 16 * j;
            if (k < K_DIM) { a0[j] = LDFRAG(k, 0); a1[j] = LDFRAG(k, 1); }
        }
        f16x8 ring[CNT + 3];
        const int nd = (p < 3) ? (CNT + 3) : (CNT + 2);
#pragma unroll
        for (int d = 0; d < CNT + 3; ++d) {
            if (d < nd)
                ring[d] = *(const f16x8*)(gbase + (p + 16 * d) * GT_PITCH);
        }
#pragma unroll
        for (int j = 0; j < 4; ++j) {
            if (p + 16 * j < K_DIM) {
#pragma unroll
                for (int t = 0; t < CNT; ++t) {
                    acc[t][0] = __builtin_amdgcn_mfma_f32_16x16x32_f16(a0[j], ring[t + j], acc[t][0], 0, 0, 0);
                    acc[t][1] = __builtin_amdgcn_mfma_f32_16x16x32_f16(a1[j], ring[t + j], acc[t][1], 0, 0, 0);
                }
            }
        }
    }
#undef LDFRAG
}

// ---------------------------------------------------------------------------
// 256 threads (4 waves) per batch row.  fp32-VALU cosine (r8-verified math)
// -> plain-f16 gT -> single-image MFMA conv.
// ---------------------------------------------------------------------------
__launch_bounds__(256, 6)
__global__ void fused_kernel(const int* __restrict__ x,
                             const int* __restrict__ mask,     // bool -> int32
                             const float* __restrict__ emb,
                             const float* __restrict__ conv_b,
                             const float* __restrict__ w1,
                             const float* __restrict__ b1,
                             const float* __restrict__ w2,
                             const float* __restrict__ b2,
                             const short* __restrict__ wAc,
                             const float* __restrict__ Lt,
                             const float* __restrict__ rnl,
                             float* __restrict__ out) {
    __shared__ __align__(16) char smem[GT_BYTES];
    __shared__ int toks[S_DIM];

    // overlay scratch (gT dead after conv)
    float* marr = (float*)(smem);
    float* red  = (float*)(smem + 1024);
    float* bw   = (float*)(smem + 2048);
    float* zp   = (float*)(smem + 3072);
    float* zsh  = (float*)(smem + 4672);
    float* hsh  = (float*)(smem + 5120);

    const int tid  = threadIdx.x;
    const int b    = blockIdx.x;
    const int lane = tid & 63;
    const int wv   = tid >> 6;
    const int n    = lane & 15;
    const int q    = lane >> 4;

    // ---- zero gT (pads stay zero; cosine writes only rows 25..224) ----
    {
        float4 z{0.f, 0.f, 0.f, 0.f};
        float4* g4 = (float4*)smem;                      // 1290 float4
        for (int j = tid; j < GT_BYTES / 16; j += 256) g4[j] = z;
    }

    const int s    = tid;
    const bool act = (s < S_DIM);
    int tok = 0, msk = 0;
    if (act) {
        tok = x[b * S_DIM + s];
        msk = mask[b * S_DIM + s];
        toks[s] = tok;
    }
    __syncthreads();

    // ---- phase 1: fp32 cosine sims (r8-verified) -> plain-f16 gT row ----
    if (act) {
        float dacc[C_DIM];
#pragma unroll
        for (int c = 0; c < C_DIM; ++c) dacc[c] = 0.f;
        float n2 = 0.f;
        const float4* er  = (const float4*)(emb + (size_t)tok * E_DIM);
        const float4* Lt4 = (const float4*)Lt;
        for (int j = 0; j < 25; ++j) {
            const float4 r = er[j];
            n2 += r.x * r.x + r.y * r.y + r.z * r.z + r.w * r.w;
            const float rv[4] = {r.x, r.y, r.z, r.w};
#pragma unroll
            for (int u = 0; u < 4; ++u) {
#pragma unroll
                for (int qq = 0; qq < 5; ++qq) {
                    const float4 a = Lt4[(j * 4 + u) * 5 + qq];
                    dacc[qq * 4 + 0] += rv[u] * a.x;
                    dacc[qq * 4 + 1] += rv[u] * a.y;
                    dacc[qq * 4 + 2] += rv[u] * a.z;
                    dacc[qq * 4 + 3] += rv[u] * a.w;
                }
            }
        }
        const float xn    = sqrtf(n2);
        const float rxn16 = (xn > 0.f) ? 16.f / xn : 0.f;
        unsigned* grow = (unsigned*)(smem + (PADW + s) * GT_PITCH);
#pragma unroll
        for (int d = 0; d < 10; ++d) {
            grow[d] = pkrtz(dacc[2 * d + 0] * rnl[2 * d + 0] * rxn16,
                            dacc[2 * d + 1] * rnl[2 * d + 1] * rxn16);
        }
        // f16 elements 20..31 remain zero (init) — matches zero A slots
    }
    __syncthreads();

    // ---- conv: waves split the 13 n-tiles (4/3/3/3) ----
    f32x4 acc[4][2];
#pragma unroll
    for (int t = 0; t < 4; ++t) {
        acc[t][0] = f32x4{0.f, 0.f, 0.f, 0.f};
        acc[t][1] = f32x4{0.f, 0.f, 0.f, 0.f};
    }
    const int nt0 = (wv == 0) ? 0 : (1 + wv * 3);      // 0,4,7,10
    const int cnt = (wv == 0) ? 4 : 3;
    const char* gbase = smem + (nt0 * 16 + n) * GT_PITCH + q * 16;
    if (wv == 0) conv_tiles<4>(wAc, gbase, acc, lane);
    else         conv_tiles<3>(wAc, gbase, acc, lane);

    __syncthreads();   // gT dead; overlay live

    // ---- epilogue: relu + bias + channel max -> marr[s]  (D = 4096*u) ----
    {
        const float inv = 1.f / 4096.f;
        float cb0[4], cb1[4];
#pragma unroll
        for (int r = 0; r < 4; ++r) {
            cb0[r] = conv_b[4 * q + r];
            cb1[r] = (q == 0) ? conv_b[16 + r] : 0.f;
        }
        for (int t = 0; t < cnt; ++t) {
            float m = 0.f;   // relu floor
#pragma unroll
            for (int r = 0; r < 4; ++r) m = fmaxf(m, acc[t][0][r] * inv + cb0[r]);
            if (q == 0) {
#pragma unroll
                for (int r = 0; r < 4; ++r) m = fmaxf(m, acc[t][1][r] * inv + cb1[r]);
            }
            m = fmaxf(m, __shfl_xor(m, 16));
            m = fmaxf(m, __shfl_xor(m, 32));
            const int ss = (nt0 + t) * 16 + n;
            if (q == 0 && ss < S_DIM) marr[ss] = m;
        }
    }
    __syncthreads();

    // ---- softmax over s: wave shuffles + 4-slot cross-wave ----
    {
        float mval = act ? ((msk != 0) ? marr[s] : -1e13f) : -1e30f;
        float lm = mval;
#pragma unroll
        for (int off = 32; off > 0; off >>= 1) lm = fmaxf(lm, __shfl_xor(lm, off));
        if (lane == 0) red[wv] = lm;
        __syncthreads();
        const float gmax = fmaxf(fmaxf(red[0], red[1]), fmaxf(red[2], red[3]));
        const float p = act ? expf(mval - gmax) : 0.f;
        float ps = p;
#pragma unroll
        for (int off = 32; off > 0; off >>= 1) ps += __shfl_xor(ps, off);
        if (lane == 0) red[4 + wv] = ps;
        __syncthreads();
        const float gsum = (red[4] + red[5]) + (red[6] + red[7]);
        if (act) bw[s] = p / gsum;
    }
    __syncthreads();

    // ---- pooling: wave w sums s in [50w, 50w+50), 2-way unrolled ----
    {
        float za0 = 0.f, zb0 = 0.f, za1 = 0.f, zb1 = 0.f;
        const int s0 = wv * 50;
        for (int ss = s0; ss < s0 + 50; ss += 2) {
            const float  w0  = bw[ss];
            const float  w1v = bw[ss + 1];
            const float* r0 = emb + (size_t)toks[ss] * E_DIM;
            const float* r1 = emb + (size_t)toks[ss + 1] * E_DIM;
            za0 += w0 * r0[lane];
            za1 += w1v * r1[lane];
            if (lane < E_DIM - 64) {
                zb0 += w0 * r0[64 + lane];
                zb1 += w1v * r1[64 + lane];
            }
        }
        zp[wv * E_DIM + lane] = za0 + za1;
        if (lane < E_DIM - 64) zp[wv * E_DIM + 64 + lane] = zb0 + zb1;
    }
    __syncthreads();
    if (tid < E_DIM)
        zsh[tid] = zp[tid] + zp[E_DIM + tid] + zp[2 * E_DIM + tid] + zp[3 * E_DIM + tid];
    __syncthreads();

    // ---- MLP ----
    if (tid < E_DIM / 2) {
        float h = b1[tid];
        for (int e = 0; e < E_DIM; ++e) h += zsh[e] * w1[e * (E_DIM / 2) + tid];
        hsh[tid] = fmaxf(h, 0.f);
    }
    __syncthreads();
    if (tid < C_DIM) {
        float o = b2[tid];
#pragma unroll
        for (int j = 0; j < E_DIM / 2; ++j) o += hsh[j] * w2[j * C_DIM + tid];
        out[b * C_DIM + tid] = o;
    }
}

// ---------------------------------------------------------------------------
extern "C" void kernel_launch(void* const* d_in, const int* in_sizes, int n_in,
                              void* d_out, int out_size, void* d_ws, size_t ws_size,
                              hipStream_t stream) {
    const int*   x      = (const int*)d_in[0];
    const int*   mask   = (const int*)d_in[2];    // bool delivered as int32
    const float* emb    = (const float*)d_in[3];
    const float* labels = (const float*)d_in[4];
    const float* conv_w = (const float*)d_in[5];
    const float* conv_b = (const float*)d_in[6];
    const float* w1     = (const float*)d_in[7];
    const float* b1     = (const float*)d_in[8];
    const float* w2     = (const float*)d_in[9];
    const float* b2     = (const float*)d_in[10];
    float*       out    = (float*)d_out;

    short* wAc = (short*)d_ws;                    // 52224 shorts
    float* Lt  = (float*)((char*)d_ws + NWC * 2); // 2000 floats
    float* rnl = Lt + C_DIM * E_DIM;              // 20 floats

    const int prep_n = NWC + C_DIM * E_DIM + C_DIM;
    prep_kernel<<<(prep_n + 255) / 256, 256, 0, stream>>>(conv_w, labels, wAc, Lt, rnl);
    fused_kernel<<<B_DIM, 256, 0, stream>>>(x, mask, emb, conv_b,
                                            w1, b1, w2, b2, wAc, Lt, rnl, out);
}